// Round 2
// baseline (110.210 us; speedup 1.0000x reference)
//
#include <hip/hip_runtime.h>
#include <math.h>

// Problem constants
#define NTOK   16384   // B*N = 16*1024
#define CIN_   66      // HID + IN_DIM
#define HID_   64
#define NCH    192     // folded columns: [z(64) | r(64) | c(64)]
#define TPB    16      // tokens per block

__device__ __forceinline__ float fast_sigmoid(float a) {
    return 1.0f / (1.0f + __expf(-a));
}
__device__ __forceinline__ float fast_tanh(float a) {
    return 1.0f - 2.0f / (__expf(2.0f * a) + 1.0f);
}

// ---------------------------------------------------------------------------
// Kernel 1: fold rnn_W[6][198][64] + rnn_b[6][64] into Wf[66][192], bf[192].
// gconv_rnn source bug => effective weight = W[:66] + 0.05*(W[66:132]+W[132:198]);
// z uses pair (0,1), r uses (2,3), hc uses (4,5) -> pre-sum the pairs.
// ---------------------------------------------------------------------------
__global__ void fold_weights(const float* __restrict__ rnn_W,
                             const float* __restrict__ rnn_b,
                             float* __restrict__ Wf,
                             float* __restrict__ bf)
{
    int idx = blockIdx.x * blockDim.x + threadIdx.x;
    if (idx >= CIN_ * NCH) return;
    int k = idx / NCH;
    int c = idx - k * NCH;
    int g = c >> 6;          // 0:z 1:r 2:c
    int j = c & 63;
    int i0 = 2 * g, i1 = 2 * g + 1;
    const float s = 0.05f;
    float v = 0.0f;
    v += rnn_W[(i0 * 198 + k) * 64 + j]
       + s * (rnn_W[(i0 * 198 + 66 + k) * 64 + j] + rnn_W[(i0 * 198 + 132 + k) * 64 + j]);
    v += rnn_W[(i1 * 198 + k) * 64 + j]
       + s * (rnn_W[(i1 * 198 + 66 + k) * 64 + j] + rnn_W[(i1 * 198 + 132 + k) * 64 + j]);
    Wf[k * NCH + c] = v;
    if (k == 0) bf[c] = rnn_b[i0 * 64 + j] + rnn_b[i1 * 64 + j];
}

// ---------------------------------------------------------------------------
// Kernel 2: fused GRU cell. 1024 blocks x 256 threads; block owns 16 tokens.
// grp = tid/16 (0..15) picks a channel slice; tok = tid%16. Weights read as
// vector global_load_dwordx4 (vmcnt — pipelines against ds_read/v_fmac; Wf is
// 50 KB, L1/L2 resident, broadcast across lanes). 16 waves/CU occupancy.
// ---------------------------------------------------------------------------
__global__ __launch_bounds__(256)
void dgcrm_gru(const float* __restrict__ x,    // [NTOK][2]
               const float* __restrict__ h,    // [NTOK][64]
               const float* __restrict__ Wf,   // [66][192]
               const float* __restrict__ bf,   // [192]
               float* __restrict__ out)        // [NTOK][64]
{
    __shared__ float C[CIN_][TPB + 1];  // combined = [x; h], [k][tok]
    __shared__ float D[CIN_][TPB + 1];  // candidate = [x; r*h]
    __shared__ float Z[HID_][TPB + 1];  // z, then overwritten with output

    const int tid = threadIdx.x;
    const int t0  = blockIdx.x * TPB;     // first global token of this block

    // ---- stage h (transposed): 16 tok x 64 ch = 1024 floats = 256 float4 ----
    {
        float4 v = ((const float4*)(h + (size_t)t0 * HID_))[tid];
        int f = tid * 4;
        int t = f >> 6;
        int c = f & 63;
        C[2 + c + 0][t] = v.x;
        C[2 + c + 1][t] = v.y;
        C[2 + c + 2][t] = v.z;
        C[2 + c + 3][t] = v.w;
    }
    // ---- stage x into rows 0,1 of both C and D ----
    if (tid < 2 * TPB) {
        int t = tid >> 1, k = tid & 1;
        float v = x[(size_t)(t0 + t) * 2 + k];
        C[k][t] = v;
        D[k][t] = v;
    }
    __syncthreads();

    const int grp = tid >> 4;   // 0..15 channel group
    const int tok = tid & 15;   // token within block

    // =================== phase 1: z (ch 0..63) and r (ch 64..127) ==========
    {
        const int ch0 = grp * 8;             // 0..120 over [z|r]
        float acc[8];
        {
            float4 b0 = *(const float4*)(bf + ch0);
            float4 b1 = *(const float4*)(bf + ch0 + 4);
            acc[0] = b0.x; acc[1] = b0.y; acc[2] = b0.z; acc[3] = b0.w;
            acc[4] = b1.x; acc[5] = b1.y; acc[6] = b1.z; acc[7] = b1.w;
        }
        for (int k = 0; k < CIN_; ++k) {
            float ck = C[k][tok];
            const float4* w4 = (const float4*)(Wf + k * NCH + ch0);
            float4 w0 = w4[0];
            float4 w1 = w4[1];
            acc[0] = fmaf(ck, w0.x, acc[0]);
            acc[1] = fmaf(ck, w0.y, acc[1]);
            acc[2] = fmaf(ck, w0.z, acc[2]);
            acc[3] = fmaf(ck, w0.w, acc[3]);
            acc[4] = fmaf(ck, w1.x, acc[4]);
            acc[5] = fmaf(ck, w1.y, acc[5]);
            acc[6] = fmaf(ck, w1.z, acc[6]);
            acc[7] = fmaf(ck, w1.w, acc[7]);
        }
        if (grp < 8) {
            // z channels ch0..ch0+7
            #pragma unroll
            for (int j = 0; j < 8; ++j)
                Z[ch0 + j][tok] = fast_sigmoid(acc[j]);
        } else {
            // r channels rb..rb+7 ; write cand = r*h into D
            const int rb = ch0 - 64;
            #pragma unroll
            for (int j = 0; j < 8; ++j)
                D[2 + rb + j][tok] = fast_sigmoid(acc[j]) * C[2 + rb + j][tok];
        }
    }
    __syncthreads();

    // =================== phase 2: hc (ch 128..191), combine ================
    {
        const int c0 = 128 + grp * 4;        // folded-col index
        float acc[4];
        {
            float4 b0 = *(const float4*)(bf + c0);
            acc[0] = b0.x; acc[1] = b0.y; acc[2] = b0.z; acc[3] = b0.w;
        }
        for (int k = 0; k < CIN_; ++k) {
            float dk = D[k][tok];
            float4 w = *(const float4*)(Wf + k * NCH + c0);
            acc[0] = fmaf(dk, w.x, acc[0]);
            acc[1] = fmaf(dk, w.y, acc[1]);
            acc[2] = fmaf(dk, w.z, acc[2]);
            acc[3] = fmaf(dk, w.w, acc[3]);
        }
        const int hb = grp * 4;              // hc channel base 0..60
        #pragma unroll
        for (int j = 0; j < 4; ++j) {
            float hc = fast_tanh(acc[j]);
            float zv = Z[hb + j][tok];       // this thread owns (hb+j, tok)
            float hv = C[2 + hb + j][tok];
            Z[hb + j][tok] = zv * hv + (1.0f - zv) * hc;  // in-place: out
        }
    }
    __syncthreads();

    // ---- coalesced write-back: out[t0+t][c..c+3] = Z[c..c+3][t] ----
    {
        int f = tid * 4;
        int t = f >> 6;
        int c = f & 63;
        float4 r;
        r.x = Z[c + 0][t];
        r.y = Z[c + 1][t];
        r.z = Z[c + 2][t];
        r.w = Z[c + 3][t];
        ((float4*)(out + (size_t)t0 * HID_))[tid] = r;
    }
}

// ---------------------------------------------------------------------------
extern "C" void kernel_launch(void* const* d_in, const int* in_sizes, int n_in,
                              void* d_out, int out_size, void* d_ws, size_t ws_size,
                              hipStream_t stream)
{
    const float* x     = (const float*)d_in[0];   // [16,1024,2]
    const float* hprev = (const float*)d_in[1];   // [16,1024,64]
    const float* rnn_W = (const float*)d_in[12];  // [6,198,64]
    const float* rnn_b = (const float*)d_in[13];  // [6,64]

    float* Wf = (float*)d_ws;                 // 66*192 floats
    float* bf = Wf + CIN_ * NCH;              // 192 floats

    fold_weights<<<(CIN_ * NCH + 255) / 256, 256, 0, stream>>>(rnn_W, rnn_b, Wf, bf);
    dgcrm_gru<<<NTOK / TPB, 256, 0, stream>>>(x, hprev, Wf, bf, (float*)d_out);
}

// Round 3
// 102.341 us; speedup vs baseline: 1.0769x; 1.0769x over previous
//
#include <hip/hip_runtime.h>
#include <math.h>

// Problem constants
#define NTOK   16384   // B*N = 16*1024
#define CIN_   66      // HID + IN_DIM
#define HID_   64
#define NCH    192     // folded columns: [z(64) | r(64) | c(64)]
#define TPB    32      // tokens per block (2 per thread)

__device__ __forceinline__ float fast_sigmoid(float a) {
    return 1.0f / (1.0f + __expf(-a));
}
__device__ __forceinline__ float fast_tanh(float a) {
    return 1.0f - 2.0f / (__expf(2.0f * a) + 1.0f);
}

// ---------------------------------------------------------------------------
// Kernel 1: fold rnn_W[6][198][64] + rnn_b[6][64] into Wf[66][192], bf[192].
// gconv_rnn source bug => effective weight = W[:66] + 0.05*(W[66:132]+W[132:198]);
// z uses pair (0,1), r uses (2,3), hc uses (4,5) -> pre-sum the pairs.
// ---------------------------------------------------------------------------
__global__ void fold_weights(const float* __restrict__ rnn_W,
                             const float* __restrict__ rnn_b,
                             float* __restrict__ Wf,
                             float* __restrict__ bf)
{
    int idx = blockIdx.x * blockDim.x + threadIdx.x;
    if (idx >= CIN_ * NCH) return;
    int k = idx / NCH;
    int c = idx - k * NCH;
    int g = c >> 6;          // 0:z 1:r 2:c
    int j = c & 63;
    int i0 = 2 * g, i1 = 2 * g + 1;
    const float s = 0.05f;
    float v = 0.0f;
    v += rnn_W[(i0 * 198 + k) * 64 + j]
       + s * (rnn_W[(i0 * 198 + 66 + k) * 64 + j] + rnn_W[(i0 * 198 + 132 + k) * 64 + j]);
    v += rnn_W[(i1 * 198 + k) * 64 + j]
       + s * (rnn_W[(i1 * 198 + 66 + k) * 64 + j] + rnn_W[(i1 * 198 + 132 + k) * 64 + j]);
    Wf[k * NCH + c] = v;
    if (k == 0) bf[c] = rnn_b[i0 * 64 + j] + rnn_b[i1 * 64 + j];
}

// ---------------------------------------------------------------------------
// Kernel 2: fused GRU cell. 512 blocks x 256 threads; block owns 32 tokens,
// each thread owns 2 tokens x (8 z/r channels | 4 c channels). Weight loads
// (global_load_dwordx4, L1/L2-resident, broadcast within 16-lane groups) are
// amortized over 16 FMAs/k. 8 waves/CU.
// ---------------------------------------------------------------------------
__global__ __launch_bounds__(256)
void dgcrm_gru(const float* __restrict__ x,    // [NTOK][2]
               const float* __restrict__ h,    // [NTOK][64]
               const float* __restrict__ Wf,   // [66][192]
               const float* __restrict__ bf,   // [192]
               float* __restrict__ out)        // [NTOK][64]
{
    __shared__ float C[CIN_][TPB + 1];  // combined = [x; h], [k][tok]
    __shared__ float D[CIN_][TPB + 1];  // candidate = [x; r*h]
    __shared__ float Z[HID_][TPB + 1];  // z, then overwritten with output

    const int tid = threadIdx.x;
    const int t0  = blockIdx.x * TPB;     // first global token of this block

    // ---- stage h (transposed): 32 tok x 64 ch = 2048 floats = 512 float4 ----
    {
        const float4* h4 = (const float4*)(h + (size_t)t0 * HID_);
        #pragma unroll
        for (int r = 0; r < 2; ++r) {
            int i = tid + r * 256;
            float4 v = h4[i];
            int f = i * 4;
            int t = f >> 6;
            int c = f & 63;
            C[2 + c + 0][t] = v.x;
            C[2 + c + 1][t] = v.y;
            C[2 + c + 2][t] = v.z;
            C[2 + c + 3][t] = v.w;
        }
    }
    // ---- stage x into rows 0,1 of both C and D ----
    if (tid < 2 * TPB) {
        int t = tid >> 1, k = tid & 1;
        float v = x[(size_t)(t0 + t) * 2 + k];
        C[k][t] = v;
        D[k][t] = v;
    }
    __syncthreads();

    const int grp  = tid >> 4;   // 0..15 channel group
    const int tokA = tid & 15;   // first token
    const int tokB = tokA + 16;  // second token

    // =================== phase 1: z (ch 0..63) and r (ch 64..127) ==========
    {
        const int ch0 = grp * 8;             // 0..120 over [z|r]
        float accA[8], accB[8];
        {
            float4 b0 = *(const float4*)(bf + ch0);
            float4 b1 = *(const float4*)(bf + ch0 + 4);
            accA[0] = b0.x; accA[1] = b0.y; accA[2] = b0.z; accA[3] = b0.w;
            accA[4] = b1.x; accA[5] = b1.y; accA[6] = b1.z; accA[7] = b1.w;
            #pragma unroll
            for (int j = 0; j < 8; ++j) accB[j] = accA[j];
        }
        for (int k = 0; k < CIN_; ++k) {
            float ckA = C[k][tokA];
            float ckB = C[k][tokB];
            const float4* w4 = (const float4*)(Wf + k * NCH + ch0);
            float4 w0 = w4[0];
            float4 w1 = w4[1];
            accA[0] = fmaf(ckA, w0.x, accA[0]);  accB[0] = fmaf(ckB, w0.x, accB[0]);
            accA[1] = fmaf(ckA, w0.y, accA[1]);  accB[1] = fmaf(ckB, w0.y, accB[1]);
            accA[2] = fmaf(ckA, w0.z, accA[2]);  accB[2] = fmaf(ckB, w0.z, accB[2]);
            accA[3] = fmaf(ckA, w0.w, accA[3]);  accB[3] = fmaf(ckB, w0.w, accB[3]);
            accA[4] = fmaf(ckA, w1.x, accA[4]);  accB[4] = fmaf(ckB, w1.x, accB[4]);
            accA[5] = fmaf(ckA, w1.y, accA[5]);  accB[5] = fmaf(ckB, w1.y, accB[5]);
            accA[6] = fmaf(ckA, w1.z, accA[6]);  accB[6] = fmaf(ckB, w1.z, accB[6]);
            accA[7] = fmaf(ckA, w1.w, accA[7]);  accB[7] = fmaf(ckB, w1.w, accB[7]);
        }
        if (grp < 8) {
            // z channels ch0..ch0+7
            #pragma unroll
            for (int j = 0; j < 8; ++j) {
                Z[ch0 + j][tokA] = fast_sigmoid(accA[j]);
                Z[ch0 + j][tokB] = fast_sigmoid(accB[j]);
            }
        } else {
            // r channels rb..rb+7 ; write cand = r*h into D
            const int rb = ch0 - 64;
            #pragma unroll
            for (int j = 0; j < 8; ++j) {
                D[2 + rb + j][tokA] = fast_sigmoid(accA[j]) * C[2 + rb + j][tokA];
                D[2 + rb + j][tokB] = fast_sigmoid(accB[j]) * C[2 + rb + j][tokB];
            }
        }
    }
    __syncthreads();

    // =================== phase 2: hc (ch 128..191), combine ================
    {
        const int c0 = 128 + grp * 4;        // folded-col index
        float accA[4], accB[4];
        {
            float4 b0 = *(const float4*)(bf + c0);
            accA[0] = b0.x; accA[1] = b0.y; accA[2] = b0.z; accA[3] = b0.w;
            #pragma unroll
            for (int j = 0; j < 4; ++j) accB[j] = accA[j];
        }
        for (int k = 0; k < CIN_; ++k) {
            float dkA = D[k][tokA];
            float dkB = D[k][tokB];
            float4 w = *(const float4*)(Wf + k * NCH + c0);
            accA[0] = fmaf(dkA, w.x, accA[0]);  accB[0] = fmaf(dkB, w.x, accB[0]);
            accA[1] = fmaf(dkA, w.y, accA[1]);  accB[1] = fmaf(dkB, w.y, accB[1]);
            accA[2] = fmaf(dkA, w.z, accA[2]);  accB[2] = fmaf(dkB, w.z, accB[2]);
            accA[3] = fmaf(dkA, w.w, accA[3]);  accB[3] = fmaf(dkB, w.w, accB[3]);
        }
        const int hb = grp * 4;              // hc channel base 0..60
        #pragma unroll
        for (int j = 0; j < 4; ++j) {
            float hcA = fast_tanh(accA[j]);
            float hcB = fast_tanh(accB[j]);
            float zvA = Z[hb + j][tokA];
            float zvB = Z[hb + j][tokB];
            float hvA = C[2 + hb + j][tokA];
            float hvB = C[2 + hb + j][tokB];
            Z[hb + j][tokA] = zvA * hvA + (1.0f - zvA) * hcA;
            Z[hb + j][tokB] = zvB * hvB + (1.0f - zvB) * hcB;
        }
    }
    __syncthreads();

    // ---- coalesced write-back: out[t0+t][c..c+3] = Z[c..c+3][t] ----
    {
        float4* o4 = (float4*)(out + (size_t)t0 * HID_);
        #pragma unroll
        for (int r = 0; r < 2; ++r) {
            int i = tid + r * 256;
            int f = i * 4;
            int t = f >> 6;
            int c = f & 63;
            float4 v;
            v.x = Z[c + 0][t];
            v.y = Z[c + 1][t];
            v.z = Z[c + 2][t];
            v.w = Z[c + 3][t];
            o4[i] = v;
        }
    }
}

// ---------------------------------------------------------------------------
extern "C" void kernel_launch(void* const* d_in, const int* in_sizes, int n_in,
                              void* d_out, int out_size, void* d_ws, size_t ws_size,
                              hipStream_t stream)
{
    const float* x     = (const float*)d_in[0];   // [16,1024,2]
    const float* hprev = (const float*)d_in[1];   // [16,1024,64]
    const float* rnn_W = (const float*)d_in[12];  // [6,198,64]
    const float* rnn_b = (const float*)d_in[13];  // [6,64]

    float* Wf = (float*)d_ws;                 // 66*192 floats
    float* bf = Wf + CIN_ * NCH;              // 192 floats

    fold_weights<<<(CIN_ * NCH + 255) / 256, 256, 0, stream>>>(rnn_W, rnn_b, Wf, bf);
    dgcrm_gru<<<NTOK / TPB, 256, 0, stream>>>(x, hprev, Wf, bf, (float*)d_out);
}

// Round 4
// 99.228 us; speedup vs baseline: 1.1107x; 1.0314x over previous
//
#include <hip/hip_runtime.h>
#include <math.h>

// Problem constants
#define NTOK   16384   // B*N = 16*1024
#define CIN_   66      // HID + IN_DIM
#define HID_   64
#define NCH    192     // folded columns: [z(64) | r(64) | c(64)]
#define TPB    32      // tokens per block (2 per thread)
#define KPAD   68      // padded k-stride for [tok][k] LDS tiles (16B-aligned, 2-way banks)

// Workspace layout (floats):
//   Wt1[16][66][8]  : phase-1 weights, grp-major, k-order = (h:0..63, x:64,65)
//   Wt2[16][66][4]  : phase-2 weights, grp-major, same k-order
//   bf[192]         : folded biases [z|r|c]
#define WT1_ELEMS (16 * 66 * 8)
#define WT2_ELEMS (16 * 66 * 4)

__device__ __forceinline__ float fast_sigmoid(float a) {
    return 1.0f / (1.0f + __expf(-a));
}
__device__ __forceinline__ float fast_tanh(float a) {
    return 1.0f - 2.0f / (__expf(2.0f * a) + 1.0f);
}

// ---------------------------------------------------------------------------
// Kernel 1: fold rnn_W[6][198][64] + rnn_b[6][64] and swizzle into streaming
// layouts. gconv_rnn source bug => effective weight =
// W[:66] + 0.05*(W[66:132]+W[132:198]); z uses pair (0,1), r (2,3), hc (4,5).
// k-order remap: knew 0..63 -> orig combined row 2+knew (h), knew 64,65 -> x.
// ---------------------------------------------------------------------------
__global__ void fold_weights(const float* __restrict__ rnn_W,
                             const float* __restrict__ rnn_b,
                             float* __restrict__ Wt1,
                             float* __restrict__ Wt2,
                             float* __restrict__ bf)
{
    int idx = blockIdx.x * blockDim.x + threadIdx.x;
    if (idx >= CIN_ * NCH) return;
    int knew = idx / NCH;
    int c    = idx - knew * NCH;
    int korig = (knew < 64) ? (knew + 2) : (knew - 64);
    int g = c >> 6;          // 0:z 1:r 2:c
    int j = c & 63;
    int i0 = 2 * g, i1 = 2 * g + 1;
    const float s = 0.05f;
    float v = 0.0f;
    v += rnn_W[(i0 * 198 + korig) * 64 + j]
       + s * (rnn_W[(i0 * 198 + 66 + korig) * 64 + j] + rnn_W[(i0 * 198 + 132 + korig) * 64 + j]);
    v += rnn_W[(i1 * 198 + korig) * 64 + j]
       + s * (rnn_W[(i1 * 198 + 66 + korig) * 64 + j] + rnn_W[(i1 * 198 + 132 + korig) * 64 + j]);

    if (g < 2) {
        int ch  = c;             // 0..127 over [z|r]
        int grp = ch >> 3;
        int jj  = ch & 7;
        Wt1[(grp * CIN_ + knew) * 8 + jj] = v;
    } else {
        int ch  = c - 128;       // 0..63
        int grp = ch >> 2;
        int jj  = ch & 3;
        Wt2[(grp * CIN_ + knew) * 4 + jj] = v;
    }
    if (knew == 0) bf[c] = rnn_b[i0 * 64 + j] + rnn_b[i1 * 64 + j];
}

// ---------------------------------------------------------------------------
// Kernel 2: fused GRU cell. 512 blocks x 256 threads; block owns 32 tokens,
// thread owns 2 tokens x (8 z/r | 4 c) channels. Activations in LDS as
// [tok][k] (stride 68) -> ds_read_b128 covers 4 k's; weights streamed from a
// contiguous per-grp region via global_load_dwordx4 (broadcast within the
// 16-lane grp, 4 lines/wave/instr, L1/L2 resident).
// ---------------------------------------------------------------------------
__global__ __launch_bounds__(256)
void dgcrm_gru(const float* __restrict__ x,    // [NTOK][2]
               const float* __restrict__ h,    // [NTOK][64]
               const float* __restrict__ Wt1,  // [16][66][8]
               const float* __restrict__ Wt2,  // [16][66][4]
               const float* __restrict__ bf,   // [192]
               float* __restrict__ out)        // [NTOK][64]
{
    __shared__ float Cs[TPB][KPAD];  // combined: k 0..63 = h, 64..65 = x
    __shared__ float Ds[TPB][KPAD];  // candidate: k 0..63 = r*h, 64..65 = x
    __shared__ float Zs[TPB][KPAD];  // z, then overwritten with output

    const int tid = threadIdx.x;
    const int t0  = blockIdx.x * TPB;

    // ---- stage h: 32 tok x 64 ch = 512 float4, direct [tok][k] b128 writes --
    {
        const float4* h4 = (const float4*)(h + (size_t)t0 * HID_);
        #pragma unroll
        for (int r = 0; r < 2; ++r) {
            int i = tid + r * 256;        // 0..511
            float4 v = h4[i];
            int t = i >> 4;               // token 0..31
            int c = (i * 4) & 63;         // k 0,4,...,60
            *(float4*)&Cs[t][c] = v;
        }
    }
    // ---- stage x into k = 64,65 of Cs and Ds ----
    if (tid < 2 * TPB) {
        int t = tid >> 1, k = tid & 1;
        float v = x[(size_t)(t0 + t) * 2 + k];
        Cs[t][64 + k] = v;
        Ds[t][64 + k] = v;
    }
    __syncthreads();

    const int grp  = tid >> 4;   // 0..15 channel group
    const int tokA = tid & 15;
    const int tokB = tokA + 16;

    // =================== phase 1: z (ch 0..63) and r (ch 64..127) ==========
    {
        const int ch0 = grp * 8;
        const float* wp = Wt1 + grp * (CIN_ * 8);
        float accA[8], accB[8];
        {
            float4 b0 = *(const float4*)(bf + ch0);
            float4 b1 = *(const float4*)(bf + ch0 + 4);
            accA[0] = b0.x; accA[1] = b0.y; accA[2] = b0.z; accA[3] = b0.w;
            accA[4] = b1.x; accA[5] = b1.y; accA[6] = b1.z; accA[7] = b1.w;
            #pragma unroll
            for (int j = 0; j < 8; ++j) accB[j] = accA[j];
        }
        #pragma unroll
        for (int kb = 0; kb < 16; ++kb) {
            float4 a4 = *(const float4*)&Cs[tokA][4 * kb];
            float4 b4 = *(const float4*)&Cs[tokB][4 * kb];
            float ca[4] = {a4.x, a4.y, a4.z, a4.w};
            float cb[4] = {b4.x, b4.y, b4.z, b4.w};
            #pragma unroll
            for (int j = 0; j < 4; ++j) {
                float4 w0 = *(const float4*)(wp + (4 * kb + j) * 8);
                float4 w1 = *(const float4*)(wp + (4 * kb + j) * 8 + 4);
                accA[0] = fmaf(ca[j], w0.x, accA[0]);  accB[0] = fmaf(cb[j], w0.x, accB[0]);
                accA[1] = fmaf(ca[j], w0.y, accA[1]);  accB[1] = fmaf(cb[j], w0.y, accB[1]);
                accA[2] = fmaf(ca[j], w0.z, accA[2]);  accB[2] = fmaf(cb[j], w0.z, accB[2]);
                accA[3] = fmaf(ca[j], w0.w, accA[3]);  accB[3] = fmaf(cb[j], w0.w, accB[3]);
                accA[4] = fmaf(ca[j], w1.x, accA[4]);  accB[4] = fmaf(cb[j], w1.x, accB[4]);
                accA[5] = fmaf(ca[j], w1.y, accA[5]);  accB[5] = fmaf(cb[j], w1.y, accB[5]);
                accA[6] = fmaf(ca[j], w1.z, accA[6]);  accB[6] = fmaf(cb[j], w1.z, accB[6]);
                accA[7] = fmaf(ca[j], w1.w, accA[7]);  accB[7] = fmaf(cb[j], w1.w, accB[7]);
            }
        }
        // tail k = 64, 65 (x rows)
        {
            float a64 = Cs[tokA][64], a65 = Cs[tokA][65];
            float b64 = Cs[tokB][64], b65 = Cs[tokB][65];
            float4 u0 = *(const float4*)(wp + 64 * 8);
            float4 u1 = *(const float4*)(wp + 64 * 8 + 4);
            float4 v0 = *(const float4*)(wp + 65 * 8);
            float4 v1 = *(const float4*)(wp + 65 * 8 + 4);
            float wu[8] = {u0.x,u0.y,u0.z,u0.w,u1.x,u1.y,u1.z,u1.w};
            float wv[8] = {v0.x,v0.y,v0.z,v0.w,v1.x,v1.y,v1.z,v1.w};
            #pragma unroll
            for (int j = 0; j < 8; ++j) {
                accA[j] = fmaf(a64, wu[j], fmaf(a65, wv[j], accA[j]));
                accB[j] = fmaf(b64, wu[j], fmaf(b65, wv[j], accB[j]));
            }
        }
        if (grp < 8) {
            float4 za0, za1, zb0, zb1;
            za0.x = fast_sigmoid(accA[0]); za0.y = fast_sigmoid(accA[1]);
            za0.z = fast_sigmoid(accA[2]); za0.w = fast_sigmoid(accA[3]);
            za1.x = fast_sigmoid(accA[4]); za1.y = fast_sigmoid(accA[5]);
            za1.z = fast_sigmoid(accA[6]); za1.w = fast_sigmoid(accA[7]);
            zb0.x = fast_sigmoid(accB[0]); zb0.y = fast_sigmoid(accB[1]);
            zb0.z = fast_sigmoid(accB[2]); zb0.w = fast_sigmoid(accB[3]);
            zb1.x = fast_sigmoid(accB[4]); zb1.y = fast_sigmoid(accB[5]);
            zb1.z = fast_sigmoid(accB[6]); zb1.w = fast_sigmoid(accB[7]);
            *(float4*)&Zs[tokA][ch0]     = za0;
            *(float4*)&Zs[tokA][ch0 + 4] = za1;
            *(float4*)&Zs[tokB][ch0]     = zb0;
            *(float4*)&Zs[tokB][ch0 + 4] = zb1;
        } else {
            const int rb = ch0 - 64;     // 0..56
            float4 ha0 = *(const float4*)&Cs[tokA][rb];
            float4 ha1 = *(const float4*)&Cs[tokA][rb + 4];
            float4 hb0 = *(const float4*)&Cs[tokB][rb];
            float4 hb1 = *(const float4*)&Cs[tokB][rb + 4];
            float4 da0, da1, db0, db1;
            da0.x = fast_sigmoid(accA[0]) * ha0.x;  da0.y = fast_sigmoid(accA[1]) * ha0.y;
            da0.z = fast_sigmoid(accA[2]) * ha0.z;  da0.w = fast_sigmoid(accA[3]) * ha0.w;
            da1.x = fast_sigmoid(accA[4]) * ha1.x;  da1.y = fast_sigmoid(accA[5]) * ha1.y;
            da1.z = fast_sigmoid(accA[6]) * ha1.z;  da1.w = fast_sigmoid(accA[7]) * ha1.w;
            db0.x = fast_sigmoid(accB[0]) * hb0.x;  db0.y = fast_sigmoid(accB[1]) * hb0.y;
            db0.z = fast_sigmoid(accB[2]) * hb0.z;  db0.w = fast_sigmoid(accB[3]) * hb0.w;
            db1.x = fast_sigmoid(accB[4]) * hb1.x;  db1.y = fast_sigmoid(accB[5]) * hb1.y;
            db1.z = fast_sigmoid(accB[6]) * hb1.z;  db1.w = fast_sigmoid(accB[7]) * hb1.w;
            *(float4*)&Ds[tokA][rb]     = da0;
            *(float4*)&Ds[tokA][rb + 4] = da1;
            *(float4*)&Ds[tokB][rb]     = db0;
            *(float4*)&Ds[tokB][rb + 4] = db1;
        }
    }
    __syncthreads();

    // =================== phase 2: hc (ch 128..191), combine ================
    {
        const int c0 = 128 + grp * 4;    // bias index
        const float* wp = Wt2 + grp * (CIN_ * 4);
        float accA[4], accB[4];
        {
            float4 b0 = *(const float4*)(bf + c0);
            accA[0] = b0.x; accA[1] = b0.y; accA[2] = b0.z; accA[3] = b0.w;
            #pragma unroll
            for (int j = 0; j < 4; ++j) accB[j] = accA[j];
        }
        #pragma unroll
        for (int kb = 0; kb < 16; ++kb) {
            float4 a4 = *(const float4*)&Ds[tokA][4 * kb];
            float4 b4 = *(const float4*)&Ds[tokB][4 * kb];
            float ca[4] = {a4.x, a4.y, a4.z, a4.w};
            float cb[4] = {b4.x, b4.y, b4.z, b4.w};
            #pragma unroll
            for (int j = 0; j < 4; ++j) {
                float4 w = *(const float4*)(wp + (4 * kb + j) * 4);
                accA[0] = fmaf(ca[j], w.x, accA[0]);  accB[0] = fmaf(cb[j], w.x, accB[0]);
                accA[1] = fmaf(ca[j], w.y, accA[1]);  accB[1] = fmaf(cb[j], w.y, accB[1]);
                accA[2] = fmaf(ca[j], w.z, accA[2]);  accB[2] = fmaf(cb[j], w.z, accB[2]);
                accA[3] = fmaf(ca[j], w.w, accA[3]);  accB[3] = fmaf(cb[j], w.w, accB[3]);
            }
        }
        // tail k = 64, 65 (x rows)
        {
            float a64 = Ds[tokA][64], a65 = Ds[tokA][65];
            float b64 = Ds[tokB][64], b65 = Ds[tokB][65];
            float4 u = *(const float4*)(wp + 64 * 4);
            float4 v = *(const float4*)(wp + 65 * 4);
            float wu[4] = {u.x, u.y, u.z, u.w};
            float wv[4] = {v.x, v.y, v.z, v.w};
            #pragma unroll
            for (int j = 0; j < 4; ++j) {
                accA[j] = fmaf(a64, wu[j], fmaf(a65, wv[j], accA[j]));
                accB[j] = fmaf(b64, wu[j], fmaf(b65, wv[j], accB[j]));
            }
        }
        const int hb = grp * 4;          // hc channel base 0..60
        float4 zA = *(const float4*)&Zs[tokA][hb];
        float4 zB = *(const float4*)&Zs[tokB][hb];
        float4 hA = *(const float4*)&Cs[tokA][hb];
        float4 hB = *(const float4*)&Cs[tokB][hb];
        float4 oA, oB;
        oA.x = zA.x * hA.x + (1.0f - zA.x) * fast_tanh(accA[0]);
        oA.y = zA.y * hA.y + (1.0f - zA.y) * fast_tanh(accA[1]);
        oA.z = zA.z * hA.z + (1.0f - zA.z) * fast_tanh(accA[2]);
        oA.w = zA.w * hA.w + (1.0f - zA.w) * fast_tanh(accA[3]);
        oB.x = zB.x * hB.x + (1.0f - zB.x) * fast_tanh(accB[0]);
        oB.y = zB.y * hB.y + (1.0f - zB.y) * fast_tanh(accB[1]);
        oB.z = zB.z * hB.z + (1.0f - zB.z) * fast_tanh(accB[2]);
        oB.w = zB.w * hB.w + (1.0f - zB.w) * fast_tanh(accB[3]);
        *(float4*)&Zs[tokA][hb] = oA;
        *(float4*)&Zs[tokB][hb] = oB;
    }
    __syncthreads();

    // ---- coalesced write-back: out[t][c..c+3] = Zs[t][c..c+3] ----
    {
        float4* o4 = (float4*)(out + (size_t)t0 * HID_);
        #pragma unroll
        for (int r = 0; r < 2; ++r) {
            int i = tid + r * 256;
            int t = i >> 4;
            int c = (i * 4) & 63;
            o4[i] = *(const float4*)&Zs[t][c];
        }
    }
}

// ---------------------------------------------------------------------------
extern "C" void kernel_launch(void* const* d_in, const int* in_sizes, int n_in,
                              void* d_out, int out_size, void* d_ws, size_t ws_size,
                              hipStream_t stream)
{
    const float* x     = (const float*)d_in[0];   // [16,1024,2]
    const float* hprev = (const float*)d_in[1];   // [16,1024,64]
    const float* rnn_W = (const float*)d_in[12];  // [6,198,64]
    const float* rnn_b = (const float*)d_in[13];  // [6,64]

    float* Wt1 = (float*)d_ws;                    // [16][66][8]
    float* Wt2 = Wt1 + WT1_ELEMS;                 // [16][66][4]
    float* bf  = Wt2 + WT2_ELEMS;                 // [192]

    fold_weights<<<(CIN_ * NCH + 255) / 256, 256, 0, stream>>>(rnn_W, rnn_b, Wt1, Wt2, bf);
    dgcrm_gru<<<NTOK / TPB, 256, 0, stream>>>(x, hprev, Wt1, Wt2, bf, (float*)d_out);
}